// Round 1
// baseline (145.953 us; speedup 1.0000x reference)
//
#include <hip/hip_runtime.h>

#define NHEADS 4
#define HDIM   64
#define BATCH  8
#define SEQ    1024
#define CH     256   // H*hd = in_dim = out_dim

// ---------------------------------------------------------------------------
// K1: proj = x @ Wp   (M=8192, K=256, N=256), fp32, 64x64 tile, 4x4/thread
// ---------------------------------------------------------------------------
__global__ __launch_bounds__(256) void gemm_proj(const float* __restrict__ x,
                                                 const float* __restrict__ Wp,
                                                 float* __restrict__ proj) {
    __shared__ __align__(16) float AsT[16][68];  // [k][row]
    __shared__ __align__(16) float Bs[16][68];   // [k][col]
    const int t  = threadIdx.x;
    const int m0 = blockIdx.x * 64;
    const int n0 = blockIdx.y * 64;
    const int ty = t >> 4, tx = t & 15;
    const int r  = t >> 2, c4 = t & 3;
    float acc[4][4] = {};
    for (int kb = 0; kb < 16; ++kb) {
        float4 av = *reinterpret_cast<const float4*>(&x[(size_t)(m0 + r) * CH + kb * 16 + c4 * 4]);
        AsT[c4 * 4 + 0][r] = av.x;
        AsT[c4 * 4 + 1][r] = av.y;
        AsT[c4 * 4 + 2][r] = av.z;
        AsT[c4 * 4 + 3][r] = av.w;
        for (int idx = t; idx < 1024; idx += 256) {
            int kr = idx >> 6, c = idx & 63;
            Bs[kr][c] = Wp[(size_t)(kb * 16 + kr) * CH + n0 + c];
        }
        __syncthreads();
#pragma unroll
        for (int k = 0; k < 16; ++k) {
            float4 a0 = *reinterpret_cast<const float4*>(&AsT[k][ty * 4]);
            float4 b0 = *reinterpret_cast<const float4*>(&Bs[k][tx * 4]);
            float a[4] = {a0.x, a0.y, a0.z, a0.w};
            float bb[4] = {b0.x, b0.y, b0.z, b0.w};
#pragma unroll
            for (int i = 0; i < 4; ++i)
#pragma unroll
                for (int j = 0; j < 4; ++j) acc[i][j] += a[i] * bb[j];
        }
        __syncthreads();
    }
#pragma unroll
    for (int i = 0; i < 4; ++i) {
        float4 v = make_float4(acc[i][0], acc[i][1], acc[i][2], acc[i][3]);
        *reinterpret_cast<float4*>(&proj[(size_t)(m0 + ty * 4 + i) * CH + n0 + tx * 4]) = v;
    }
}

// ---------------------------------------------------------------------------
// K2: s_l[row,h] = proj[row,h,:]·w_l ; s_r likewise. One wave per (row,h).
// ---------------------------------------------------------------------------
__global__ __launch_bounds__(256) void slsr_kernel(const float* __restrict__ proj,
                                                   const float* __restrict__ Ws,
                                                   float* __restrict__ sl,
                                                   float* __restrict__ sr) {
    const int wid  = blockIdx.x * 4 + (threadIdx.x >> 6);
    const int lane = threadIdx.x & 63;
    const int row  = wid >> 2, h = wid & 3;
    float p = proj[(size_t)row * CH + h * HDIM + lane];
    float a = p * Ws[lane];
    float c = p * Ws[64 + lane];
#pragma unroll
    for (int off = 32; off; off >>= 1) {
        a += __shfl_down(a, off);
        c += __shfl_down(c, off);
    }
    if (lane == 0) {
        sl[row * 4 + h] = a;
        sr[row * 4 + h] = c;
    }
}

// ---------------------------------------------------------------------------
// K3: fused attention. Block = (i-tile 64, head, batch). 4 waves split m.
//     Unnormalized accumulation: num = sum e*proj, den = sum e; no max pass
//     (scores O(10), clamp at 60 -> exp safe in fp32; masked e == 0 exactly).
// ---------------------------------------------------------------------------
__global__ __launch_bounds__(256, 2) void attn_kernel(const float* __restrict__ x,
                                                      const float* __restrict__ adj,
                                                      const float* __restrict__ proj,
                                                      const float* __restrict__ sl,
                                                      const float* __restrict__ sr,
                                                      const float* __restrict__ Ws,
                                                      const float* __restrict__ bias,
                                                      float* __restrict__ out) {
    __shared__ __align__(16) float eT[4][32][68];   // per-wave e, transposed [m][i]
    __shared__ __align__(16) float cbuf[64][68];    // acc combine buffer
    __shared__ float denb[4][64];
    __shared__ float srl[SEQ];

    const int t    = threadIdx.x;
    const int w    = t >> 6;
    const int lane = t & 63;
    const int i0   = blockIdx.x * 64;
    const int h    = blockIdx.y;
    const int b    = blockIdx.z;

    const float wa = Ws[2 * HDIM];

    for (int idx = t; idx < SEQ; idx += 256) srl[idx] = sr[(size_t)(b * SEQ + idx) * 4 + h];
    __syncthreads();

    const float sl_i  = sl[(size_t)(b * SEQ + i0 + lane) * 4 + h];
    const size_t arow = (size_t)(b * SEQ + i0 + lane) * SEQ;
    const int ig = lane >> 3, dg = lane & 7;
    const size_t pbase = (size_t)b * SEQ * CH + h * HDIM + dg * 8;

    float acc[8][8] = {};
    float den = 0.f;

    for (int cidx = 0; cidx < 8; ++cidx) {
        const int mb = cidx * 128 + w * 32;
        // stage A: lane = row i, compute e for this wave's 32 m values
#pragma unroll
        for (int k4 = 0; k4 < 8; ++k4) {
            const int m = mb + k4 * 4;
            float4 av = *reinterpret_cast<const float4*>(&adj[arow + m]);
            float aj[4] = {av.x, av.y, av.z, av.w};
#pragma unroll
            for (int j = 0; j < 4; ++j) {
                float s = sl_i + srl[m + j] + aj[j] * wa;
                s = s > 0.f ? s : 0.2f * s;
                float e = (aj[j] <= 1e-5f) ? 0.f : __expf(fminf(s, 60.f));
                den += e;
                eT[w][k4 * 4 + j][lane] = e;
            }
        }
        // stage B: PV, lane = (ig,dg), 8i x 8d register tile, same wave -> no barrier
#pragma unroll 4
        for (int kk = 0; kk < 32; ++kk) {
            const int m = mb + kk;
            float4 e0 = *reinterpret_cast<const float4*>(&eT[w][kk][ig * 8]);
            float4 e1 = *reinterpret_cast<const float4*>(&eT[w][kk][ig * 8 + 4]);
            float4 p0 = *reinterpret_cast<const float4*>(&proj[pbase + (size_t)m * CH]);
            float4 p1 = *reinterpret_cast<const float4*>(&proj[pbase + (size_t)m * CH + 4]);
            float ev[8] = {e0.x, e0.y, e0.z, e0.w, e1.x, e1.y, e1.z, e1.w};
            float pv[8] = {p0.x, p0.y, p0.z, p0.w, p1.x, p1.y, p1.z, p1.w};
#pragma unroll
            for (int ii = 0; ii < 8; ++ii)
#pragma unroll
                for (int dd = 0; dd < 8; ++dd) acc[ii][dd] += ev[ii] * pv[dd];
        }
    }
    denb[w][lane] = den;
    __syncthreads();

    // combine per-wave partial acc into cbuf (disjoint row groups per round)
    for (int r = 0; r < 4; ++r) {
        const int g = (w + r) & 3;
        if ((ig >> 1) == g) {
#pragma unroll
            for (int rr = 0; rr < 8; ++rr) {
                const int row = ig * 8 + rr;
                float4* c0 = reinterpret_cast<float4*>(&cbuf[row][dg * 8]);
                float4* c1 = reinterpret_cast<float4*>(&cbuf[row][dg * 8 + 4]);
                float4 v0 = make_float4(acc[rr][0], acc[rr][1], acc[rr][2], acc[rr][3]);
                float4 v1 = make_float4(acc[rr][4], acc[rr][5], acc[rr][6], acc[rr][7]);
                if (r == 0) {
                    *c0 = v0; *c1 = v1;
                } else {
                    float4 o0 = *c0, o1 = *c1;
                    o0.x += v0.x; o0.y += v0.y; o0.z += v0.z; o0.w += v0.w;
                    o1.x += v1.x; o1.y += v1.y; o1.z += v1.z; o1.w += v1.w;
                    *c0 = o0; *c1 = o1;
                }
            }
        }
        __syncthreads();
    }

    // epilogue: out = lrelu(x + msg + bias, 0.5)
    const int row = t >> 2, q = t & 3;
    const float dsum = denb[0][row] + denb[1][row] + denb[2][row] + denb[3][row];
    const float inv = 1.f / dsum;
    const size_t obase = (size_t)(b * SEQ + i0 + row) * CH + h * HDIM + q * 16;
#pragma unroll
    for (int j4 = 0; j4 < 4; ++j4) {
        float4 m4 = *reinterpret_cast<const float4*>(&cbuf[row][q * 16 + j4 * 4]);
        float4 x4 = *reinterpret_cast<const float4*>(&x[obase + j4 * 4]);
        float4 b4 = *reinterpret_cast<const float4*>(&bias[h * HDIM + q * 16 + j4 * 4]);
        float v[4] = {m4.x * inv + x4.x + b4.x, m4.y * inv + x4.y + b4.y,
                      m4.z * inv + x4.z + b4.z, m4.w * inv + x4.w + b4.w};
#pragma unroll
        for (int j = 0; j < 4; ++j) v[j] = v[j] > 0.f ? v[j] : 0.5f * v[j];
        *reinterpret_cast<float4*>(&out[obase + j4 * 4]) = make_float4(v[0], v[1], v[2], v[3]);
    }
}

// ---------------------------------------------------------------------------
// K4: copy adj into output chunk 2 (reference returns (out, adj))
// ---------------------------------------------------------------------------
__global__ void adjcopy(const float* __restrict__ adj, float* __restrict__ dst, int n4) {
    int idx = blockIdx.x * blockDim.x + threadIdx.x;
    int stride = gridDim.x * blockDim.x;
    const float4* s = reinterpret_cast<const float4*>(adj);
    float4* d = reinterpret_cast<float4*>(dst);
    for (int i = idx; i < n4; i += stride) d[i] = s[i];
}

extern "C" void kernel_launch(void* const* d_in, const int* in_sizes, int n_in,
                              void* d_out, int out_size, void* d_ws, size_t ws_size,
                              hipStream_t stream) {
    const float* x    = (const float*)d_in[0];
    const float* adj  = (const float*)d_in[1];
    const float* Wp   = (const float*)d_in[2];
    const float* Ws   = (const float*)d_in[3];
    const float* bias = (const float*)d_in[4];
    float* out      = (float*)d_out;
    float* out_adj  = out + (size_t)BATCH * SEQ * CH;  // 2,097,152

    // scratch: proj (8 MB) + sl + sr (128 KB each). Prefer d_ws; else borrow the
    // adj-output region (33.5 MB), which is overwritten last by adjcopy.
    const size_t need = ((size_t)BATCH * SEQ * CH + 2 * (size_t)BATCH * SEQ * NHEADS) * sizeof(float);
    float* scratch = (ws_size >= need) ? (float*)d_ws : out_adj;
    float* proj = scratch;
    float* sl   = proj + (size_t)BATCH * SEQ * CH;
    float* sr   = sl + (size_t)BATCH * SEQ * NHEADS;

    gemm_proj<<<dim3(128, 4), 256, 0, stream>>>(x, Wp, proj);
    slsr_kernel<<<dim3(8192), 256, 0, stream>>>(proj, Ws, sl, sr);
    attn_kernel<<<dim3(16, NHEADS, BATCH), 256, 0, stream>>>(x, adj, proj, sl, sr, Ws, bias, out);
    adjcopy<<<2048, 256, 0, stream>>>(adj, out_adj, (BATCH * SEQ * SEQ) / 4);
}

// Round 2
// 99.087 us; speedup vs baseline: 1.4730x; 1.4730x over previous
//
#include <hip/hip_runtime.h>

#define NHEADS 4
#define HDIM   64
#define BATCH  8
#define SEQ    1024
#define CH     256   // H*hd = in_dim = out_dim

typedef float  f32x4  __attribute__((ext_vector_type(4)));
typedef __bf16 bf16x8 __attribute__((ext_vector_type(8)));
typedef short  s16x8  __attribute__((ext_vector_type(8)));
union FU { s16x8 s; bf16x8 b; };

__device__ inline unsigned short f2bf(float f) {
    unsigned u = __float_as_uint(f);
    return (unsigned short)((u + 0x7fffu + ((u >> 16) & 1u)) >> 16);
}
__device__ inline float bf2f(unsigned short u) {
    return __uint_as_float(((unsigned)u) << 16);
}

// ---------------------------------------------------------------------------
// K1: proj = x @ Wp   (M=8192, K=256, N=256), fp32, 64x64 tile, 4x4/thread
// ---------------------------------------------------------------------------
__global__ __launch_bounds__(256) void gemm_proj(const float* __restrict__ x,
                                                 const float* __restrict__ Wp,
                                                 float* __restrict__ proj) {
    __shared__ __align__(16) float AsT[16][68];  // [k][row]
    __shared__ __align__(16) float Bs[16][68];   // [k][col]
    const int t  = threadIdx.x;
    const int m0 = blockIdx.x * 64;
    const int n0 = blockIdx.y * 64;
    const int ty = t >> 4, tx = t & 15;
    const int r  = t >> 2, c4 = t & 3;
    float acc[4][4] = {};
    for (int kb = 0; kb < 16; ++kb) {
        float4 av = *reinterpret_cast<const float4*>(&x[(size_t)(m0 + r) * CH + kb * 16 + c4 * 4]);
        AsT[c4 * 4 + 0][r] = av.x;
        AsT[c4 * 4 + 1][r] = av.y;
        AsT[c4 * 4 + 2][r] = av.z;
        AsT[c4 * 4 + 3][r] = av.w;
        for (int idx = t; idx < 1024; idx += 256) {
            int kr = idx >> 6, c = idx & 63;
            Bs[kr][c] = Wp[(size_t)(kb * 16 + kr) * CH + n0 + c];
        }
        __syncthreads();
#pragma unroll
        for (int k = 0; k < 16; ++k) {
            float4 a0 = *reinterpret_cast<const float4*>(&AsT[k][ty * 4]);
            float4 b0 = *reinterpret_cast<const float4*>(&Bs[k][tx * 4]);
            float a[4] = {a0.x, a0.y, a0.z, a0.w};
            float bb[4] = {b0.x, b0.y, b0.z, b0.w};
#pragma unroll
            for (int i = 0; i < 4; ++i)
#pragma unroll
                for (int j = 0; j < 4; ++j) acc[i][j] += a[i] * bb[j];
        }
        __syncthreads();
    }
#pragma unroll
    for (int i = 0; i < 4; ++i) {
        float4 v = make_float4(acc[i][0], acc[i][1], acc[i][2], acc[i][3]);
        *reinterpret_cast<float4*>(&proj[(size_t)(m0 + ty * 4 + i) * CH + n0 + tx * 4]) = v;
    }
}

// ---------------------------------------------------------------------------
// K2: transpose+cast proj -> projT bf16 [b][h][d=64][m=1024], plus sl/sr [b][h][m].
//     Block = (m-tile 32, b). LDS tile [m=32][d=256] bf16, row stride 284 u16
//     (dword-stride 142 ≡ 14 mod 32 -> 2-way conflicts only on all phases).
// ---------------------------------------------------------------------------
__global__ __launch_bounds__(256) void trans_slsr(const float* __restrict__ proj,
                                                  const float* __restrict__ Ws,
                                                  unsigned short* __restrict__ projT,
                                                  float* __restrict__ sl,
                                                  float* __restrict__ sr) {
    __shared__ unsigned short T[32][284];
    __shared__ float wbuf[128];
    const int t  = threadIdx.x;
    const int m0 = blockIdx.x * 32;
    const int b  = blockIdx.y;
    if (t < 128) wbuf[t] = Ws[t];
    const int c = t & 63;   // float4 column: d = 4c
    const int q = t >> 6;   // row offset
#pragma unroll
    for (int r = 0; r < 8; ++r) {
        const int m = q + r * 4;
        float4 v = *reinterpret_cast<const float4*>(&proj[(size_t)(b * SEQ + m0 + m) * CH + 4 * c]);
        unsigned p0 = (unsigned)f2bf(v.x) | ((unsigned)f2bf(v.y) << 16);
        unsigned p1 = (unsigned)f2bf(v.z) | ((unsigned)f2bf(v.w) << 16);
        *reinterpret_cast<unsigned*>(&T[m][4 * c])     = p0;
        *reinterpret_cast<unsigned*>(&T[m][4 * c + 2]) = p1;
    }
    __syncthreads();
    // projT writer: thread t owns full-d row t (h = t>>6, d = t&63)
    {
        unsigned short rowbuf[32];
#pragma unroll
        for (int m = 0; m < 32; ++m) rowbuf[m] = T[m][t];
        unsigned short* dst = &projT[((size_t)(b * NHEADS + (t >> 6)) * HDIM + (t & 63)) * SEQ + m0];
#pragma unroll
        for (int s = 0; s < 4; ++s) {
            uint4 o;
            o.x = (unsigned)rowbuf[s * 8 + 0] | ((unsigned)rowbuf[s * 8 + 1] << 16);
            o.y = (unsigned)rowbuf[s * 8 + 2] | ((unsigned)rowbuf[s * 8 + 3] << 16);
            o.z = (unsigned)rowbuf[s * 8 + 4] | ((unsigned)rowbuf[s * 8 + 5] << 16);
            o.w = (unsigned)rowbuf[s * 8 + 6] | ((unsigned)rowbuf[s * 8 + 7] << 16);
            *reinterpret_cast<uint4*>(dst + s * 8) = o;
        }
    }
    // sl/sr: threads 0..127, (m = t&31, h = t>>5)
    if (t < 128) {
        const int m = t & 31, h2 = t >> 5;
        float a = 0.f, r2 = 0.f;
#pragma unroll 8
        for (int d = 0; d < HDIM; ++d) {
            float v = bf2f(T[m][h2 * HDIM + d]);
            a  += v * wbuf[d];
            r2 += v * wbuf[HDIM + d];
        }
        sl[(b * NHEADS + h2) * SEQ + m0 + m] = a;
        sr[(b * NHEADS + h2) * SEQ + m0 + m] = r2;
    }
}

// ---------------------------------------------------------------------------
// K3: fused attention, MFMA PV. Block = (i-tile 64, h, b), wave w owns 16 rows.
//     Zero LDS, zero barriers. e computed straight into the A-fragment layout
//     (lane l: i = l&15, m-slice = (l>>4)*8). B-frags are dwordx4 from projT.
//     num = sum e*proj via mfma_f32_16x16x32_bf16; den on VALU + shfl_xor.
// ---------------------------------------------------------------------------
template <bool FUSE_ADJ>
__global__ __launch_bounds__(256) void attn_mfma(const float* __restrict__ x,
                                                 const float* __restrict__ adj,
                                                 const unsigned short* __restrict__ projT,
                                                 const float* __restrict__ sl,
                                                 const float* __restrict__ sr,
                                                 const float* __restrict__ Ws,
                                                 const float* __restrict__ bias,
                                                 float* __restrict__ out,
                                                 float* __restrict__ out_adj) {
    const int t = threadIdx.x;
    const int w = t >> 6, l = t & 63;
    const int i0 = blockIdx.x * 64 + w * 16;
    const int h = blockIdx.y, b = blockIdx.z;
    const float wa = Ws[2 * HDIM];
    const int il = l & 15, g = l >> 4;
    const int i = i0 + il;

    const float sl_i = sl[(b * NHEADS + h) * SEQ + i];
    const size_t arow = ((size_t)b * SEQ + i) * SEQ + g * 8;
    const float* srp = sr + (b * NHEADS + h) * SEQ + g * 8;
    const unsigned short* pT = projT + ((size_t)(b * NHEADS + h) * HDIM + il) * SEQ + g * 8;

    f32x4 acc0 = 0.f, acc1 = 0.f, acc2 = 0.f, acc3 = 0.f;
    float den = 0.f;

#pragma unroll 2
    for (int mt = 0; mt < SEQ; mt += 32) {
        FU bf0, bf1, bf2, bf3;
        bf0.s = *reinterpret_cast<const s16x8*>(pT + mt);
        bf1.s = *reinterpret_cast<const s16x8*>(pT + mt + 16 * SEQ);
        bf2.s = *reinterpret_cast<const s16x8*>(pT + mt + 32 * SEQ);
        bf3.s = *reinterpret_cast<const s16x8*>(pT + mt + 48 * SEQ);
        float4 a0 = *reinterpret_cast<const float4*>(adj + arow + mt);
        float4 a1 = *reinterpret_cast<const float4*>(adj + arow + mt + 4);
        float4 s0 = *reinterpret_cast<const float4*>(srp + mt);
        float4 s1 = *reinterpret_cast<const float4*>(srp + mt + 4);
        if (FUSE_ADJ && h == 0) {
            *reinterpret_cast<float4*>(out_adj + arow + mt)     = a0;
            *reinterpret_cast<float4*>(out_adj + arow + mt + 4) = a1;
        }
        float aj[8] = {a0.x, a0.y, a0.z, a0.w, a1.x, a1.y, a1.z, a1.w};
        float sv[8] = {s0.x, s0.y, s0.z, s0.w, s1.x, s1.y, s1.z, s1.w};
        FU af;
#pragma unroll
        for (int j = 0; j < 8; ++j) {
            float s = sl_i + sv[j] + aj[j] * wa;
            s = fmaxf(s, 0.2f * s);                       // leaky_relu 0.2
            float e = (aj[j] <= 1e-5f) ? 0.f : __expf(fminf(s, 60.f));
            den += e;
            af.s[j] = (short)f2bf(e);
        }
        acc0 = __builtin_amdgcn_mfma_f32_16x16x32_bf16(af.b, bf0.b, acc0, 0, 0, 0);
        acc1 = __builtin_amdgcn_mfma_f32_16x16x32_bf16(af.b, bf1.b, acc1, 0, 0, 0);
        acc2 = __builtin_amdgcn_mfma_f32_16x16x32_bf16(af.b, bf2.b, acc2, 0, 0, 0);
        acc3 = __builtin_amdgcn_mfma_f32_16x16x32_bf16(af.b, bf3.b, acc3, 0, 0, 0);
    }
    den += __shfl_xor(den, 16);
    den += __shfl_xor(den, 32);   // all lanes: den for i = i0 + (l&15)

    // epilogue: C/D layout col = l&15, row = g*4 + q
#pragma unroll
    for (int q = 0; q < 4; ++q) {
        const float dq = __shfl(den, g * 4 + q);
        const float inv = 1.f / dq;
        const size_t ob = ((size_t)b * SEQ + i0 + g * 4 + q) * CH + h * HDIM + il;
        float v0 = acc0[q] * inv + x[ob]      + bias[h * HDIM + il];
        float v1 = acc1[q] * inv + x[ob + 16] + bias[h * HDIM + 16 + il];
        float v2 = acc2[q] * inv + x[ob + 32] + bias[h * HDIM + 32 + il];
        float v3 = acc3[q] * inv + x[ob + 48] + bias[h * HDIM + 48 + il];
        out[ob]      = fmaxf(v0, 0.5f * v0);
        out[ob + 16] = fmaxf(v1, 0.5f * v1);
        out[ob + 32] = fmaxf(v2, 0.5f * v2);
        out[ob + 48] = fmaxf(v3, 0.5f * v3);
    }
}

// ---------------------------------------------------------------------------
// K4 (fallback when scratch lives in out_adj): copy adj into output chunk 2
// ---------------------------------------------------------------------------
__global__ void adjcopy(const float* __restrict__ adj, float* __restrict__ dst, int n4) {
    int idx = blockIdx.x * blockDim.x + threadIdx.x;
    int stride = gridDim.x * blockDim.x;
    const float4* s = reinterpret_cast<const float4*>(adj);
    float4* d = reinterpret_cast<float4*>(dst);
    for (int i = idx; i < n4; i += stride) d[i] = s[i];
}

extern "C" void kernel_launch(void* const* d_in, const int* in_sizes, int n_in,
                              void* d_out, int out_size, void* d_ws, size_t ws_size,
                              hipStream_t stream) {
    const float* x    = (const float*)d_in[0];
    const float* adj  = (const float*)d_in[1];
    const float* Wp   = (const float*)d_in[2];
    const float* Ws   = (const float*)d_in[3];
    const float* bias = (const float*)d_in[4];
    float* out     = (float*)d_out;
    float* out_adj = out + (size_t)BATCH * SEQ * CH;  // 2,097,152 floats in

    // scratch: proj fp32 (8MB) + projT bf16 (4MB) + sl + sr (128KB each)
    const size_t nProj = (size_t)BATCH * SEQ * CH;
    const size_t nSc   = (size_t)BATCH * NHEADS * SEQ;
    const size_t need  = nProj * 4 + nProj * 2 + 2 * nSc * 4;
    const bool use_ws  = (ws_size >= need);
    char* scratch = use_ws ? (char*)d_ws : (char*)out_adj;
    float*          proj  = (float*)scratch;
    unsigned short* projT = (unsigned short*)(scratch + nProj * 4);
    float*          sl    = (float*)(scratch + nProj * 4 + nProj * 2);
    float*          sr    = sl + nSc;

    gemm_proj<<<dim3(128, 4), 256, 0, stream>>>(x, Wp, proj);
    trans_slsr<<<dim3(32, BATCH), 256, 0, stream>>>(proj, Ws, projT, sl, sr);
    if (use_ws) {
        attn_mfma<true><<<dim3(16, NHEADS, BATCH), 256, 0, stream>>>(
            x, adj, projT, sl, sr, Ws, bias, out, out_adj);
    } else {
        attn_mfma<false><<<dim3(16, NHEADS, BATCH), 256, 0, stream>>>(
            x, adj, projT, sl, sr, Ws, bias, out, out_adj);
        adjcopy<<<2048, 256, 0, stream>>>(adj, out_adj, (BATCH * SEQ * SEQ) / 4);
    }
}

// Round 3
// 75.426 us; speedup vs baseline: 1.9350x; 1.3137x over previous
//
#include <hip/hip_runtime.h>

#define NHEADS 4
#define HDIM   64
#define BATCH  8
#define SEQ    1024
#define CH     256   // H*hd = in_dim = out_dim

typedef float  f32x4  __attribute__((ext_vector_type(4)));
typedef __bf16 bf16x8 __attribute__((ext_vector_type(8)));
typedef short  s16x8  __attribute__((ext_vector_type(8)));
union FU { s16x8 s; bf16x8 b; };

__device__ inline unsigned short f2bf(float f) {
    unsigned u = __float_as_uint(f);
    return (unsigned short)((u + 0x7fffu + ((u >> 16) & 1u)) >> 16);
}

// ---------------------------------------------------------------------------
// K0: WpT[ch][k] = bf16(Wp[k][ch])   (256x256, tiny)
// ---------------------------------------------------------------------------
__global__ __launch_bounds__(256) void wpt_cast(const float* __restrict__ Wp,
                                                unsigned short* __restrict__ WpT) {
    __shared__ float T[32][33];
    const int t = threadIdx.x;
    const int kt = blockIdx.x * 32, ct = blockIdx.y * 32;
    const int r = t >> 3, c4 = (t & 7) * 4;
    float4 v = *reinterpret_cast<const float4*>(&Wp[(size_t)(kt + r) * CH + ct + c4]);
    T[r][c4 + 0] = v.x; T[r][c4 + 1] = v.y; T[r][c4 + 2] = v.z; T[r][c4 + 3] = v.w;
    __syncthreads();
    unsigned p0 = (unsigned)f2bf(T[c4 + 0][r]) | ((unsigned)f2bf(T[c4 + 1][r]) << 16);
    unsigned p1 = (unsigned)f2bf(T[c4 + 2][r]) | ((unsigned)f2bf(T[c4 + 3][r]) << 16);
    uint2 o = make_uint2(p0, p1);
    *reinterpret_cast<uint2*>(&WpT[(size_t)(ct + r) * CH + kt + c4]) = o;
}

// ---------------------------------------------------------------------------
// K1': projT = (x @ Wp)^T via MFMA: D[ch][m] = WpT·x^T. Block = 64 x-rows,
//      wave w = head w (ch range w*64..+64). Writes projT bf16 [b][h][d][m]
//      + sl/sr from fp32 accumulators. No LDS, no barriers.
// ---------------------------------------------------------------------------
__global__ __launch_bounds__(256, 2) void proj_fused(const float* __restrict__ x,
                                                     const unsigned short* __restrict__ WpT,
                                                     const float* __restrict__ Ws,
                                                     unsigned short* __restrict__ projT,
                                                     float* __restrict__ sl,
                                                     float* __restrict__ sr) {
    const int t = threadIdx.x, w = t >> 6, l = t & 63, il = l & 15, g = l >> 4;
    const int row0 = blockIdx.x * 64;           // global x row (= b*1024 + n0)
    const int b = row0 >> 10, n0 = row0 & 1023;

    const unsigned short* Ap = WpT + (size_t)(w * 64 + il) * CH + g * 8;
    const float*          Bp = x + (size_t)(row0 + il) * CH + g * 8;

    f32x4 acc[4][4] = {};   // [ai(ch)][bj(m)]
    for (int kt = 0; kt < 8; ++kt) {
        FU a[4], bb[4];
#pragma unroll
        for (int ai = 0; ai < 4; ++ai)
            a[ai].s = *reinterpret_cast<const s16x8*>(Ap + (size_t)ai * 16 * CH + kt * 32);
#pragma unroll
        for (int bj = 0; bj < 4; ++bj) {
            const float* p = Bp + (size_t)bj * 16 * CH + kt * 32;
            float4 v0 = *reinterpret_cast<const float4*>(p);
            float4 v1 = *reinterpret_cast<const float4*>(p + 4);
            bb[bj].b[0] = (__bf16)v0.x; bb[bj].b[1] = (__bf16)v0.y;
            bb[bj].b[2] = (__bf16)v0.z; bb[bj].b[3] = (__bf16)v0.w;
            bb[bj].b[4] = (__bf16)v1.x; bb[bj].b[5] = (__bf16)v1.y;
            bb[bj].b[6] = (__bf16)v1.z; bb[bj].b[7] = (__bf16)v1.w;
        }
#pragma unroll
        for (int ai = 0; ai < 4; ++ai)
#pragma unroll
            for (int bj = 0; bj < 4; ++bj)
                acc[ai][bj] = __builtin_amdgcn_mfma_f32_16x16x32_bf16(a[ai].b, bb[bj].b, acc[ai][bj], 0, 0, 0);
    }

    // projT store: D row = ch = w*64 + ai*16 + g*4 + q, col m = n0 + bj*16 + il
    unsigned short* pTb = projT + ((size_t)(b * NHEADS + w) * HDIM) * SEQ + n0;
#pragma unroll
    for (int ai = 0; ai < 4; ++ai)
#pragma unroll
        for (int bj = 0; bj < 4; ++bj)
#pragma unroll
            for (int q = 0; q < 4; ++q) {
                const int d = ai * 16 + g * 4 + q;
                pTb[(size_t)d * SEQ + bj * 16 + il] = f2bf(acc[ai][bj][q]);
            }

    // sl/sr for head w from fp32 accumulators
    float4 wlv[4], wrv[4];
#pragma unroll
    for (int ai = 0; ai < 4; ++ai) {
        wlv[ai] = *reinterpret_cast<const float4*>(&Ws[ai * 16 + g * 4]);
        wrv[ai] = *reinterpret_cast<const float4*>(&Ws[HDIM + ai * 16 + g * 4]);
    }
#pragma unroll
    for (int bj = 0; bj < 4; ++bj) {
        float pl = 0.f, pr = 0.f;
#pragma unroll
        for (int ai = 0; ai < 4; ++ai) {
            float wl4[4] = {wlv[ai].x, wlv[ai].y, wlv[ai].z, wlv[ai].w};
            float wr4[4] = {wrv[ai].x, wrv[ai].y, wrv[ai].z, wrv[ai].w};
#pragma unroll
            for (int q = 0; q < 4; ++q) {
                pl += acc[ai][bj][q] * wl4[q];
                pr += acc[ai][bj][q] * wr4[q];
            }
        }
        pl += __shfl_xor(pl, 16); pl += __shfl_xor(pl, 32);
        pr += __shfl_xor(pr, 16); pr += __shfl_xor(pr, 32);
        if (l < 16) {
            sl[(size_t)(b * NHEADS + w) * SEQ + n0 + bj * 16 + il] = pl;
            sr[(size_t)(b * NHEADS + w) * SEQ + n0 + bj * 16 + il] = pr;
        }
    }
}

// ---------------------------------------------------------------------------
// K3: fused attention. Block = (i-tile 32, h, b); 4 waves split m (256 each).
//     Per wave: 2 A-frags (i rows), 4 B-frags (d), den via MFMA with ones-B.
//     LDS combine at the end. h==0 blocks also stream adj -> out_adj.
// ---------------------------------------------------------------------------
template <bool FUSE_ADJ>
__global__ __launch_bounds__(256, 4) void attn2(const float* __restrict__ x,
                                                const float* __restrict__ adj,
                                                const unsigned short* __restrict__ projT,
                                                const float* __restrict__ sl,
                                                const float* __restrict__ sr,
                                                const float* __restrict__ Ws,
                                                const float* __restrict__ bias,
                                                float* __restrict__ out,
                                                float* __restrict__ out_adj) {
    __shared__ float part[4][32][68];   // [wave][i-row][d]; col 64 = den

    const int t = threadIdx.x;
    const int w = t >> 6, l = t & 63, il = l & 15, g = l >> 4;
    const int i0 = blockIdx.x * 32;
    const int h = blockIdx.y, b = blockIdx.z;
    const int mb = w * 256;
    const float wa = Ws[2 * HDIM];

    const float sl0 = sl[(size_t)(b * NHEADS + h) * SEQ + i0 + il];
    const float sl1 = sl[(size_t)(b * NHEADS + h) * SEQ + i0 + 16 + il];
    const float* srp = sr + (size_t)(b * NHEADS + h) * SEQ + mb + g * 8;
    const unsigned short* pT = projT + ((size_t)(b * NHEADS + h) * HDIM + il) * SEQ + mb + g * 8;
    const size_t arow0 = ((size_t)(b * SEQ + i0 + il)) * SEQ + mb + g * 8;
    const size_t arow1 = arow0 + (size_t)16 * SEQ;

    FU onesf;
#pragma unroll
    for (int j = 0; j < 8; ++j) onesf.s[j] = (short)0x3F80;  // bf16 1.0

    f32x4 acc[2][4] = {};
    f32x4 dacc[2] = {};

#pragma unroll 2
    for (int it = 0; it < 8; ++it) {
        const int mt = it * 32;
        FU bf[4];
#pragma unroll
        for (int bj = 0; bj < 4; ++bj)
            bf[bj].s = *reinterpret_cast<const s16x8*>(pT + mt + (size_t)bj * 16 * SEQ);
        float4 a00 = *reinterpret_cast<const float4*>(adj + arow0 + mt);
        float4 a01 = *reinterpret_cast<const float4*>(adj + arow0 + mt + 4);
        float4 a10 = *reinterpret_cast<const float4*>(adj + arow1 + mt);
        float4 a11 = *reinterpret_cast<const float4*>(adj + arow1 + mt + 4);
        float4 s0  = *reinterpret_cast<const float4*>(srp + mt);
        float4 s1  = *reinterpret_cast<const float4*>(srp + mt + 4);
        if (FUSE_ADJ && h == 0) {
            *reinterpret_cast<float4*>(out_adj + arow0 + mt)     = a00;
            *reinterpret_cast<float4*>(out_adj + arow0 + mt + 4) = a01;
            *reinterpret_cast<float4*>(out_adj + arow1 + mt)     = a10;
            *reinterpret_cast<float4*>(out_adj + arow1 + mt + 4) = a11;
        }
        float aj0[8] = {a00.x, a00.y, a00.z, a00.w, a01.x, a01.y, a01.z, a01.w};
        float aj1[8] = {a10.x, a10.y, a10.z, a10.w, a11.x, a11.y, a11.z, a11.w};
        float sv[8]  = {s0.x, s0.y, s0.z, s0.w, s1.x, s1.y, s1.z, s1.w};
        FU af0, af1;
#pragma unroll
        for (int j = 0; j < 8; ++j) {
            float sA = fmaf(aj0[j], wa, sl0) + sv[j];
            sA = __builtin_amdgcn_fmed3f(sA, 0.2f * sA, 60.f);   // lrelu + clamp
            float eA = (aj0[j] <= 1e-5f) ? 0.f : __expf(sA);
            af0.b[j] = (__bf16)eA;
            float sB = fmaf(aj1[j], wa, sl1) + sv[j];
            sB = __builtin_amdgcn_fmed3f(sB, 0.2f * sB, 60.f);
            float eB = (aj1[j] <= 1e-5f) ? 0.f : __expf(sB);
            af1.b[j] = (__bf16)eB;
        }
#pragma unroll
        for (int bj = 0; bj < 4; ++bj) {
            acc[0][bj] = __builtin_amdgcn_mfma_f32_16x16x32_bf16(af0.b, bf[bj].b, acc[0][bj], 0, 0, 0);
            acc[1][bj] = __builtin_amdgcn_mfma_f32_16x16x32_bf16(af1.b, bf[bj].b, acc[1][bj], 0, 0, 0);
        }
        dacc[0] = __builtin_amdgcn_mfma_f32_16x16x32_bf16(af0.b, onesf.b, dacc[0], 0, 0, 0);
        dacc[1] = __builtin_amdgcn_mfma_f32_16x16x32_bf16(af1.b, onesf.b, dacc[1], 0, 0, 0);
    }

    // dump partial results
#pragma unroll
    for (int f = 0; f < 2; ++f)
#pragma unroll
        for (int bj = 0; bj < 4; ++bj)
#pragma unroll
            for (int q = 0; q < 4; ++q)
                part[w][f * 16 + g * 4 + q][bj * 16 + il] = acc[f][bj][q];
    if (il == 0) {
#pragma unroll
        for (int f = 0; f < 2; ++f)
#pragma unroll
            for (int q = 0; q < 4; ++q)
                part[w][f * 16 + g * 4 + q][64] = dacc[f][q];
    }
    __syncthreads();

    // final combine + epilogue: thread t -> row = t>>3 (32), dc = (t&7)*8
    const int row = t >> 3, dc = (t & 7) * 8;
    float den = part[0][row][64] + part[1][row][64] + part[2][row][64] + part[3][row][64];
    const float inv = 1.f / den;
    float m8[8] = {};
#pragma unroll
    for (int wv = 0; wv < 4; ++wv) {
        float4 u0 = *reinterpret_cast<const float4*>(&part[wv][row][dc]);
        float4 u1 = *reinterpret_cast<const float4*>(&part[wv][row][dc + 4]);
        m8[0] += u0.x; m8[1] += u0.y; m8[2] += u0.z; m8[3] += u0.w;
        m8[4] += u1.x; m8[5] += u1.y; m8[6] += u1.z; m8[7] += u1.w;
    }
    const size_t ob = ((size_t)(b * SEQ + i0 + row)) * CH + h * HDIM + dc;
    float4 x0 = *reinterpret_cast<const float4*>(&x[ob]);
    float4 x1 = *reinterpret_cast<const float4*>(&x[ob + 4]);
    float4 b0 = *reinterpret_cast<const float4*>(&bias[h * HDIM + dc]);
    float4 b1 = *reinterpret_cast<const float4*>(&bias[h * HDIM + dc + 4]);
    float xv[8] = {x0.x, x0.y, x0.z, x0.w, x1.x, x1.y, x1.z, x1.w};
    float bv[8] = {b0.x, b0.y, b0.z, b0.w, b1.x, b1.y, b1.z, b1.w};
    float o[8];
#pragma unroll
    for (int j = 0; j < 8; ++j) {
        float v = fmaf(m8[j], inv, xv[j]) + bv[j];
        o[j] = fmaxf(v, 0.5f * v);
    }
    *reinterpret_cast<float4*>(&out[ob])     = make_float4(o[0], o[1], o[2], o[3]);
    *reinterpret_cast<float4*>(&out[ob + 4]) = make_float4(o[4], o[5], o[6], o[7]);
}

// ---------------------------------------------------------------------------
// K4 (fallback): copy adj into output chunk 2
// ---------------------------------------------------------------------------
__global__ void adjcopy(const float* __restrict__ adj, float* __restrict__ dst, int n4) {
    int idx = blockIdx.x * blockDim.x + threadIdx.x;
    int stride = gridDim.x * blockDim.x;
    const float4* s = reinterpret_cast<const float4*>(adj);
    float4* d = reinterpret_cast<float4*>(dst);
    for (int i = idx; i < n4; i += stride) d[i] = s[i];
}

extern "C" void kernel_launch(void* const* d_in, const int* in_sizes, int n_in,
                              void* d_out, int out_size, void* d_ws, size_t ws_size,
                              hipStream_t stream) {
    const float* x    = (const float*)d_in[0];
    const float* adj  = (const float*)d_in[1];
    const float* Wp   = (const float*)d_in[2];
    const float* Ws   = (const float*)d_in[3];
    const float* bias = (const float*)d_in[4];
    float* out     = (float*)d_out;
    float* out_adj = out + (size_t)BATCH * SEQ * CH;

    // scratch: WpT bf16 (128KB) + projT bf16 (4MB) + sl + sr (128KB each)
    const size_t nProj = (size_t)BATCH * SEQ * CH;
    const size_t nSc   = (size_t)BATCH * NHEADS * SEQ;
    const size_t need  = CH * CH * 2 + nProj * 2 + 2 * nSc * 4;
    const bool use_ws  = (ws_size >= need);
    char* scratch = use_ws ? (char*)d_ws : (char*)out_adj;
    unsigned short* WpT   = (unsigned short*)scratch;
    unsigned short* projT = (unsigned short*)(scratch + (size_t)CH * CH * 2);
    float*          sl    = (float*)(scratch + (size_t)CH * CH * 2 + nProj * 2);
    float*          sr    = sl + nSc;

    wpt_cast<<<dim3(8, 8), 256, 0, stream>>>(Wp, WpT);
    proj_fused<<<dim3(128), 256, 0, stream>>>(x, WpT, Ws, projT, sl, sr);
    if (use_ws) {
        attn2<true><<<dim3(32, NHEADS, BATCH), 256, 0, stream>>>(
            x, adj, projT, sl, sr, Ws, bias, out, out_adj);
    } else {
        attn2<false><<<dim3(32, NHEADS, BATCH), 256, 0, stream>>>(
            x, adj, projT, sl, sr, Ws, bias, out, out_adj);
        adjcopy<<<2048, 256, 0, stream>>>(adj, out_adj, (BATCH * SEQ * SEQ) / 4);
    }
}